// Round 4
// baseline (418.936 us; speedup 1.0000x reference)
//
#include <hip/hip_runtime.h>
#include <cstdint>

#define QEPS 1e-6f

typedef int v4i __attribute__((ext_vector_type(4)));
typedef int v8i __attribute__((ext_vector_type(8)));
typedef float v4f __attribute__((ext_vector_type(4)));

__device__ __forceinline__ void gl_lds16(const void* g, void* l) {
  __builtin_amdgcn_global_load_lds(
      (const __attribute__((address_space(1))) void*)g,
      (__attribute__((address_space(3))) void*)l, 16, 0, 0);
}

// Encode integer q in [-8,7] (as float) to OCP fp8 e4m3 byte, exact.
__device__ __forceinline__ uint8_t enc_e4m3(float q) {
  const int idx = (int)q + 8;  // 0..15
  const unsigned long long lo = 0xB8C0C4C8CACCCED0ull;  // q=-8..-1 (LSB first)
  const unsigned long long hi = 0x4E4C4A4844403800ull;  // q= 0..7
  const unsigned long long tbl = (idx < 8) ? lo : hi;
  return (uint8_t)(tbl >> ((idx & 7) * 8));
}

// ---------------- Kernel 1: weight quantization -> fp8 e4m3 ----------------
__global__ __launch_bounds__(256) void wquant_kernel(const float* __restrict__ w,
                                                     uint8_t* __restrict__ qw,
                                                     float* __restrict__ wscale) {
  const int n = blockIdx.x;
  const int t = threadIdx.x;
  const float4* wrow = (const float4*)(w + (size_t)n * 4096);
  float4 v[4];
  float am = 0.f;
#pragma unroll
  for (int i = 0; i < 4; ++i) {
    v[i] = wrow[i * 256 + t];
    am = fmaxf(am, fmaxf(fmaxf(fabsf(v[i].x), fabsf(v[i].y)),
                         fmaxf(fabsf(v[i].z), fabsf(v[i].w))));
  }
#pragma unroll
  for (int off = 32; off > 0; off >>= 1)
    am = fmaxf(am, __shfl_down(am, off));
  __shared__ float wm[4];
  if ((t & 63) == 0) wm[t >> 6] = am;
  __syncthreads();
  const float rowmax = fmaxf(fmaxf(wm[0], wm[1]), fmaxf(wm[2], wm[3]));
  const float scale = fmaxf(rowmax, QEPS) / 7.0f;
  if (t == 0) wscale[n] = scale;
  uchar4* qrow = (uchar4*)(qw + (size_t)n * 4096);
#pragma unroll
  for (int i = 0; i < 4; ++i) {
    uchar4 q;
    q.x = enc_e4m3(fminf(fmaxf(rintf(v[i].x / scale), -8.f), 7.f));
    q.y = enc_e4m3(fminf(fmaxf(rintf(v[i].y / scale), -8.f), 7.f));
    q.z = enc_e4m3(fminf(fmaxf(rintf(v[i].z / scale), -8.f), 7.f));
    q.w = enc_e4m3(fminf(fmaxf(rintf(v[i].w / scale), -8.f), 7.f));
    qrow[i * 256 + t] = q;
  }
}

// ---------------- Kernel 2: FWHT + activation quantization -> fp8 ----------------
// One WAVE per row; identical butterfly tree to the reference (bit-identical fp32).
__global__ __launch_bounds__(256) void xquant_kernel(const float* __restrict__ x,
                                                     uint8_t* __restrict__ qx,
                                                     float* __restrict__ sx) {
  const int m = blockIdx.x * 4 + (threadIdx.x >> 6);
  const int g = threadIdx.x & 63;
  const float4* xrow = (const float4*)(x + (size_t)m * 4096);
  float4 v[16];
#pragma unroll
  for (int j = 0; j < 16; ++j) v[j] = xrow[j * 64 + g];

  // h = 1
#pragma unroll
  for (int j = 0; j < 16; ++j) {
    float a0 = v[j].x, b0 = v[j].y, a1 = v[j].z, b1 = v[j].w;
    v[j].x = a0 + b0; v[j].y = a0 - b0;
    v[j].z = a1 + b1; v[j].w = a1 - b1;
  }
  // h = 2
#pragma unroll
  for (int j = 0; j < 16; ++j) {
    float a0 = v[j].x, b0 = v[j].z, a1 = v[j].y, b1 = v[j].w;
    v[j].x = a0 + b0; v[j].z = a0 - b0;
    v[j].y = a1 + b1; v[j].w = a1 - b1;
  }
  // h = 4..128 : cross-lane
#pragma unroll
  for (int d = 1; d < 64; d <<= 1) {
    const bool low = (g & d) == 0;
#pragma unroll
    for (int j = 0; j < 16; ++j) {
      float px = __shfl_xor(v[j].x, d);
      float py = __shfl_xor(v[j].y, d);
      float pz = __shfl_xor(v[j].z, d);
      float pw = __shfl_xor(v[j].w, d);
      v[j].x = low ? (v[j].x + px) : (px - v[j].x);
      v[j].y = low ? (v[j].y + py) : (py - v[j].y);
      v[j].z = low ? (v[j].z + pz) : (pz - v[j].z);
      v[j].w = low ? (v[j].w + pw) : (pw - v[j].w);
    }
  }
  // h = 256..2048 : register pairs
#pragma unroll
  for (int d = 1; d < 16; d <<= 1) {
#pragma unroll
    for (int j = 0; j < 16; ++j) {
      if ((j & d) == 0) {
        float4 a = v[j], b = v[j + d];
        v[j].x = a.x + b.x; v[j].y = a.y + b.y;
        v[j].z = a.z + b.z; v[j].w = a.w + b.w;
        v[j + d].x = a.x - b.x; v[j + d].y = a.y - b.y;
        v[j + d].z = a.z - b.z; v[j + d].w = a.w - b.w;
      }
    }
  }

  float am = 0.f;
#pragma unroll
  for (int j = 0; j < 16; ++j)
    am = fmaxf(am, fmaxf(fmaxf(fabsf(v[j].x), fabsf(v[j].y)),
                         fmaxf(fabsf(v[j].z), fabsf(v[j].w))));
#pragma unroll
  for (int off = 32; off > 0; off >>= 1)
    am = fmaxf(am, __shfl_xor(am, off));

  const float inv64 = 1.0f / 64.0f;
  const float sxv = fmaxf(am * inv64, QEPS) * (1.0f / 7.0f);
  if (g == 0) sx[m] = sxv;

  uchar4* qrow = (uchar4*)(qx + (size_t)m * 4096);
#pragma unroll
  for (int j = 0; j < 16; ++j) {
    uchar4 q;
    q.x = enc_e4m3(fminf(fmaxf(rintf((v[j].x * inv64) / sxv), -8.f), 7.f));
    q.y = enc_e4m3(fminf(fmaxf(rintf((v[j].y * inv64) / sxv), -8.f), 7.f));
    q.z = enc_e4m3(fminf(fmaxf(rintf((v[j].z * inv64) / sxv), -8.f), 7.f));
    q.w = enc_e4m3(fminf(fmaxf(rintf((v[j].w * inv64) / sxv), -8.f), 7.f));
    qrow[j * 64 + g] = q;
  }
}

// ---------------- Kernel 3: MX-fp8 GEMM, 256x256 tile, 2-phase K-loop ----------
// BM=BN=256, BK=128; 512 threads = 8 waves (2M x 4N); per-wave output 128x64.
// LDS double-buffered 128 KiB; chunk c of row r stored at c ^ (r&7), swizzle
// applied at the global source so global_load_lds stays linear.
// Round-4 changes vs r3 (cycle model: r3 = fully serial port/MFMA alternation):
//  1. NO explicit lgkmcnt(0) before MFMA clusters — the compiler emits
//     counted per-MFMA lgkm waits (m97 asm evidence), so the LDS port drains
//     UNDER the MFMA cluster instead of before it.
//  2. Staging distance = 2 tiles: prologue stages tiles 0,1; tile kt stages
//     kt+2 into buf[cur] right after the mid-tile __syncthreads proves
//     buf[cur] fully read. The only vmcnt drain (inside __syncthreads) is a
//     full K-tile (~4000 cy) after issue -> staging latency fully hidden
//     (r3 drained ~550 cy after issue, paying naked HBM latency per tile).
#define BM 256
#define BN 256
#define BK 128

union frag_u { v8i v; v4i h[2]; };

#define MFMA_HALF(MB)                                                         \
  do {                                                                        \
    __builtin_amdgcn_s_setprio(1);                                            \
    _Pragma("unroll") for (int i_ = 0; i_ < 4; ++i_)                          \
        _Pragma("unroll") for (int j_ = 0; j_ < 4; ++j_)                      \
            acc[(MB) + i_][j_] =                                              \
                __builtin_amdgcn_mfma_scale_f32_16x16x128_f8f6f4(             \
                    a[i_].v, b[j_].v, acc[(MB) + i_][j_], 0, 0, 0,            \
                    0x7F7F7F7F, 0, 0x7F7F7F7F);                               \
    __builtin_amdgcn_s_setprio(0);                                            \
  } while (0)

#define LDA4(BASE)                                                            \
  do {                                                                        \
    _Pragma("unroll") for (int i_ = 0; i_ < 4; ++i_) {                        \
      const int o_ = arow[(BASE) + i_];                                       \
      a[i_].h[0] = *(const v4i*)(As_c + o_);                                  \
      a[i_].h[1] = *(const v4i*)(As_c + (o_ ^ 16));                           \
    }                                                                         \
  } while (0)

#define LDB4                                                                  \
  do {                                                                        \
    _Pragma("unroll") for (int j_ = 0; j_ < 4; ++j_) {                        \
      const int o_ = brow[j_];                                                \
      b[j_].h[0] = *(const v4i*)(Bs_c + o_);                                  \
      b[j_].h[1] = *(const v4i*)(Bs_c + (o_ ^ 16));                           \
    }                                                                         \
  } while (0)

#define STAGE8(ABUF, BBUF, KOFF)                                              \
  do {                                                                        \
    _Pragma("unroll") for (int s_ = 0; s_ < 4; ++s_) {                        \
      gl_lds16(ga + (size_t)s_ * 64 * 4096 + (KOFF), (ABUF) + s_ * 8192 + ldst); \
      gl_lds16(gb + (size_t)s_ * 64 * 4096 + (KOFF), (BBUF) + s_ * 8192 + ldst); \
    }                                                                         \
  } while (0)

__global__ __launch_bounds__(512, 2) void gemm_kernel(const uint8_t* __restrict__ qx,
                                                      const uint8_t* __restrict__ qw,
                                                      const float* __restrict__ sx,
                                                      const float* __restrict__ wscale,
                                                      const float* __restrict__ bias,
                                                      float* __restrict__ out) {
  __shared__ uint8_t As[2][BM * BK] __attribute__((aligned(16)));  // 2 x 32 KB
  __shared__ uint8_t Bs[2][BN * BK] __attribute__((aligned(16)));  // 2 x 32 KB

  const int t = threadIdx.x;
  // bijective XCD swizzle: 512 blocks, 8 XCDs, 64 consecutive swz ids per XCD
  const int bid = blockIdx.y * gridDim.x + blockIdx.x;
  const int swz = ((bid & 7) << 6) | (bid >> 3);
  const int bx = swz & 15;   // n-tile (4096/256 = 16)
  const int by = swz >> 4;   // m-tile (8192/256 = 32)
  const int m0 = by * BM;
  const int n0 = bx * BN;

  const int lane = t & 63;
  const int wave = t >> 6;
  const int wr = wave >> 2;  // 0..1
  const int wc = wave & 3;   // 0..3
  const int lr = lane & 15;
  const int lq = lane >> 4;
  const int r7 = lr & 7;
  const int c0 = ((2 * lq) ^ r7) << 4;

  v4f acc[8][4] = {};

  // staging: 4 segments of 64 rows per operand per K-tile. Thread t covers
  // row rA = t>>3 of its segment, stored chunk t&7 <- logical chunk (t&7)^(rA&7).
  const int rA = t >> 3;
  const int csrc = (((t & 7) ^ (rA & 7)) << 4);
  const uint8_t* ga = qx + (size_t)(m0 + rA) * 4096 + csrc;
  const uint8_t* gb = qw + (size_t)(n0 + rA) * 4096 + csrc;
  const int ldst = t * 16;

  int arow[8], brow[4];
#pragma unroll
  for (int mt = 0; mt < 8; ++mt)
    arow[mt] = (wr * 128 + mt * 16 + lr) * BK + c0;
#pragma unroll
  for (int nt = 0; nt < 4; ++nt)
    brow[nt] = (wc * 64 + nt * 16 + lr) * BK + c0;

  // prologue: stage K-tile 0 -> buf0 and K-tile 1 -> buf1
  STAGE8(As[0], Bs[0], 0);
  STAGE8(As[1], Bs[1], 128);
  __syncthreads();  // startup drain: tiles 0 and 1 resident

  for (int kt = 0; kt < 32; ++kt) {
    const uint8_t* As_c = As[kt & 1];
    const uint8_t* Bs_c = Bs[kt & 1];
    frag_u a[4], b[4];

    // ---- phase A: row-half 0, all 4 B tiles (16 ds_read_b128) ----
    LDA4(0);
    LDB4;
    __builtin_amdgcn_s_barrier();
    MFMA_HALF(0);  // compiler-counted lgkm waits: port drains under MFMA
    __builtin_amdgcn_s_barrier();

    // ---- phase B: row-half 1 (8 ds_read_b128) ----
    LDA4(4);
    // lgkm(0) + vmcnt(0) + barrier. lgkm: all waves done reading buf[cur]
    // (safe to overwrite). vmcnt: drains tile kt+1's loads, issued a full
    // K-tile ago -> long landed, ~free. Publishes buf[kt+1].
    __syncthreads();
    if (kt < 30) {
      // stage K-tile kt+2 into the buffer we just finished reading; its
      // drain point is tile kt+1's __syncthreads, ~4000 cy away.
      STAGE8(As[kt & 1], Bs[kt & 1], (kt + 2) << 7);
    }
    MFMA_HALF(4);
    __builtin_amdgcn_s_barrier();  // end of tile kt
  }

  // epilogue: y = qy * sx[m] * ws[n] + bias[n]; C/D: col=lane&15, row=(lane>>4)*4+reg
  float wv[4], bv[4];
#pragma unroll
  for (int nt = 0; nt < 4; ++nt) {
    const int n = n0 + wc * 64 + nt * 16 + lr;
    wv[nt] = wscale[n];
    bv[nt] = bias[n];
  }
#pragma unroll
  for (int mt = 0; mt < 8; ++mt) {
#pragma unroll
    for (int r = 0; r < 4; ++r) {
      const int m = m0 + wr * 128 + mt * 16 + lq * 4 + r;
      const float sm = sx[m];
#pragma unroll
      for (int nt = 0; nt < 4; ++nt) {
        const int n = n0 + wc * 64 + nt * 16 + lr;
        out[(size_t)m * 4096 + n] = acc[mt][nt][r] * sm * wv[nt] + bv[nt];
      }
    }
  }
}

extern "C" void kernel_launch(void* const* d_in, const int* in_sizes, int n_in,
                              void* d_out, int out_size, void* d_ws, size_t ws_size,
                              hipStream_t stream) {
  const float* x = (const float*)d_in[0];
  const float* w = (const float*)d_in[1];
  const float* bias = (const float*)d_in[2];
  float* out = (float*)d_out;

  uint8_t* qx = (uint8_t*)d_ws;
  uint8_t* qw = qx + (size_t)8192 * 4096;
  float* wscale = (float*)(qw + (size_t)4096 * 4096);
  float* sxp = wscale + 4096;

  wquant_kernel<<<4096, 256, 0, stream>>>(w, qw, wscale);
  xquant_kernel<<<2048, 256, 0, stream>>>(x, qx, sxp);
  dim3 grid(4096 / BN, 8192 / BM);
  gemm_kernel<<<grid, 512, 0, stream>>>(qx, qw, sxp, wscale, bias, out);
}

// Round 5
// 407.326 us; speedup vs baseline: 1.0285x; 1.0285x over previous
//
#include <hip/hip_runtime.h>
#include <cstdint>

#define QEPS 1e-6f

typedef int v4i __attribute__((ext_vector_type(4)));
typedef int v8i __attribute__((ext_vector_type(8)));
typedef float v4f __attribute__((ext_vector_type(4)));

__device__ __forceinline__ void gl_lds16(const void* g, void* l) {
  __builtin_amdgcn_global_load_lds(
      (const __attribute__((address_space(1))) void*)g,
      (__attribute__((address_space(3))) void*)l, 16, 0, 0);
}

// Encode integer q in [-8,7] (as float) to OCP fp8 e4m3 byte, exact.
__device__ __forceinline__ uint8_t enc_e4m3(float q) {
  const int idx = (int)q + 8;  // 0..15
  const unsigned long long lo = 0xB8C0C4C8CACCCED0ull;  // q=-8..-1 (LSB first)
  const unsigned long long hi = 0x4E4C4A4844403800ull;  // q= 0..7
  const unsigned long long tbl = (idx < 8) ? lo : hi;
  return (uint8_t)(tbl >> ((idx & 7) * 8));
}

// ---------------- Kernel 1: weight quantization -> fp8 e4m3 ----------------
__global__ __launch_bounds__(256) void wquant_kernel(const float* __restrict__ w,
                                                     uint8_t* __restrict__ qw,
                                                     float* __restrict__ wscale) {
  const int n = blockIdx.x;
  const int t = threadIdx.x;
  const float4* wrow = (const float4*)(w + (size_t)n * 4096);
  float4 v[4];
  float am = 0.f;
#pragma unroll
  for (int i = 0; i < 4; ++i) {
    v[i] = wrow[i * 256 + t];
    am = fmaxf(am, fmaxf(fmaxf(fabsf(v[i].x), fabsf(v[i].y)),
                         fmaxf(fabsf(v[i].z), fabsf(v[i].w))));
  }
#pragma unroll
  for (int off = 32; off > 0; off >>= 1)
    am = fmaxf(am, __shfl_down(am, off));
  __shared__ float wm[4];
  if ((t & 63) == 0) wm[t >> 6] = am;
  __syncthreads();
  const float rowmax = fmaxf(fmaxf(wm[0], wm[1]), fmaxf(wm[2], wm[3]));
  const float scale = fmaxf(rowmax, QEPS) / 7.0f;
  if (t == 0) wscale[n] = scale;
  uchar4* qrow = (uchar4*)(qw + (size_t)n * 4096);
#pragma unroll
  for (int i = 0; i < 4; ++i) {
    uchar4 q;
    q.x = enc_e4m3(fminf(fmaxf(rintf(v[i].x / scale), -8.f), 7.f));
    q.y = enc_e4m3(fminf(fmaxf(rintf(v[i].y / scale), -8.f), 7.f));
    q.z = enc_e4m3(fminf(fmaxf(rintf(v[i].z / scale), -8.f), 7.f));
    q.w = enc_e4m3(fminf(fmaxf(rintf(v[i].w / scale), -8.f), 7.f));
    qrow[i * 256 + t] = q;
  }
}

// ---------------- Kernel 2: FWHT + activation quantization -> fp8 ----------------
// One WAVE per row; identical butterfly tree to the reference (bit-identical fp32).
__global__ __launch_bounds__(256) void xquant_kernel(const float* __restrict__ x,
                                                     uint8_t* __restrict__ qx,
                                                     float* __restrict__ sx) {
  const int m = blockIdx.x * 4 + (threadIdx.x >> 6);
  const int g = threadIdx.x & 63;
  const float4* xrow = (const float4*)(x + (size_t)m * 4096);
  float4 v[16];
#pragma unroll
  for (int j = 0; j < 16; ++j) v[j] = xrow[j * 64 + g];

  // h = 1
#pragma unroll
  for (int j = 0; j < 16; ++j) {
    float a0 = v[j].x, b0 = v[j].y, a1 = v[j].z, b1 = v[j].w;
    v[j].x = a0 + b0; v[j].y = a0 - b0;
    v[j].z = a1 + b1; v[j].w = a1 - b1;
  }
  // h = 2
#pragma unroll
  for (int j = 0; j < 16; ++j) {
    float a0 = v[j].x, b0 = v[j].z, a1 = v[j].y, b1 = v[j].w;
    v[j].x = a0 + b0; v[j].z = a0 - b0;
    v[j].y = a1 + b1; v[j].w = a1 - b1;
  }
  // h = 4..128 : cross-lane
#pragma unroll
  for (int d = 1; d < 64; d <<= 1) {
    const bool low = (g & d) == 0;
#pragma unroll
    for (int j = 0; j < 16; ++j) {
      float px = __shfl_xor(v[j].x, d);
      float py = __shfl_xor(v[j].y, d);
      float pz = __shfl_xor(v[j].z, d);
      float pw = __shfl_xor(v[j].w, d);
      v[j].x = low ? (v[j].x + px) : (px - v[j].x);
      v[j].y = low ? (v[j].y + py) : (py - v[j].y);
      v[j].z = low ? (v[j].z + pz) : (pz - v[j].z);
      v[j].w = low ? (v[j].w + pw) : (pw - v[j].w);
    }
  }
  // h = 256..2048 : register pairs
#pragma unroll
  for (int d = 1; d < 16; d <<= 1) {
#pragma unroll
    for (int j = 0; j < 16; ++j) {
      if ((j & d) == 0) {
        float4 a = v[j], b = v[j + d];
        v[j].x = a.x + b.x; v[j].y = a.y + b.y;
        v[j].z = a.z + b.z; v[j].w = a.w + b.w;
        v[j + d].x = a.x - b.x; v[j + d].y = a.y - b.y;
        v[j + d].z = a.z - b.z; v[j + d].w = a.w - b.w;
      }
    }
  }

  float am = 0.f;
#pragma unroll
  for (int j = 0; j < 16; ++j)
    am = fmaxf(am, fmaxf(fmaxf(fabsf(v[j].x), fabsf(v[j].y)),
                         fmaxf(fabsf(v[j].z), fabsf(v[j].w))));
#pragma unroll
  for (int off = 32; off > 0; off >>= 1)
    am = fmaxf(am, __shfl_xor(am, off));

  const float inv64 = 1.0f / 64.0f;
  const float sxv = fmaxf(am * inv64, QEPS) * (1.0f / 7.0f);
  if (g == 0) sx[m] = sxv;

  uchar4* qrow = (uchar4*)(qx + (size_t)m * 4096);
#pragma unroll
  for (int j = 0; j < 16; ++j) {
    uchar4 q;
    q.x = enc_e4m3(fminf(fmaxf(rintf((v[j].x * inv64) / sxv), -8.f), 7.f));
    q.y = enc_e4m3(fminf(fmaxf(rintf((v[j].y * inv64) / sxv), -8.f), 7.f));
    q.z = enc_e4m3(fminf(fmaxf(rintf((v[j].z * inv64) / sxv), -8.f), 7.f));
    q.w = enc_e4m3(fminf(fmaxf(rintf((v[j].w * inv64) / sxv), -8.f), 7.f));
    qrow[j * 64 + g] = q;
  }
}

// ---------------- Kernel 3: MX-fp8 GEMM, 256x256 tile, free-run K-loop ----------
// BM=BN=256, BK=128; 512 threads = 8 waves (2M x 4N); per-wave output 128x64.
// LDS double-buffered 128 KiB; chunk c of row r stored at c ^ (r&7), swizzle
// applied at the global source so global_load_lds stays linear.
// Round-5: r1..r4 all measured ~36% MfmaUtil with per-K-tile time == SUM of
// MFMA + LDS-read + stage + conflict cycles (zero overlap) — the phase
// barriers + full lgkm drains serialized port vs matrix pipe. This version
// has NO intra-tile barriers and NO explicit lgkm waits: per tile one
// compiler-scheduled block of 24 ds_read_b128 + 32 MFMA (fine-grained
// counted lgkm interleave, m97 asm evidence), then:
//   s_barrier   (every wave issued its last MFMA => its reads completed
//                => buf[cur] fully consumed by all waves)
//   STAGE8(kt+2 -> buf[cur])           (overwrite the consumed buffer)
//   s_waitcnt vmcnt(8)                 (kt+1 landed; kt+2's 8 still flying;
//                                       never drains to 0 in the main loop)
//   s_barrier                          (publish buf[kt+1] to all waves)
// Waves de-phase freely inside the tile (2 waves/SIMD: one wave's reads run
// under the sibling's MFMAs, m114). No sched_barrier anywhere (m141/r2).
#define BM 256
#define BN 256
#define BK 128

union frag_u { v8i v; v4i h[2]; };

#define MFMA_HALF(MB)                                                         \
  do {                                                                        \
    __builtin_amdgcn_s_setprio(1);                                            \
    _Pragma("unroll") for (int i_ = 0; i_ < 4; ++i_)                          \
        _Pragma("unroll") for (int j_ = 0; j_ < 4; ++j_)                      \
            acc[(MB) + i_][j_] =                                              \
                __builtin_amdgcn_mfma_scale_f32_16x16x128_f8f6f4(             \
                    a[i_].v, b[j_].v, acc[(MB) + i_][j_], 0, 0, 0,            \
                    0x7F7F7F7F, 0, 0x7F7F7F7F);                               \
    __builtin_amdgcn_s_setprio(0);                                            \
  } while (0)

#define LDA4(BASE)                                                            \
  do {                                                                        \
    _Pragma("unroll") for (int i_ = 0; i_ < 4; ++i_) {                        \
      const int o_ = arow[(BASE) + i_];                                       \
      a[i_].h[0] = *(const v4i*)(As_c + o_);                                  \
      a[i_].h[1] = *(const v4i*)(As_c + (o_ ^ 16));                           \
    }                                                                         \
  } while (0)

#define LDB4                                                                  \
  do {                                                                        \
    _Pragma("unroll") for (int j_ = 0; j_ < 4; ++j_) {                        \
      const int o_ = brow[j_];                                                \
      b[j_].h[0] = *(const v4i*)(Bs_c + o_);                                  \
      b[j_].h[1] = *(const v4i*)(Bs_c + (o_ ^ 16));                           \
    }                                                                         \
  } while (0)

#define STAGE8(ABUF, BBUF, KOFF)                                              \
  do {                                                                        \
    _Pragma("unroll") for (int s_ = 0; s_ < 4; ++s_) {                        \
      gl_lds16(ga + (size_t)s_ * 64 * 4096 + (KOFF), (ABUF) + s_ * 8192 + ldst); \
      gl_lds16(gb + (size_t)s_ * 64 * 4096 + (KOFF), (BBUF) + s_ * 8192 + ldst); \
    }                                                                         \
  } while (0)

__global__ __launch_bounds__(512, 2) void gemm_kernel(const uint8_t* __restrict__ qx,
                                                      const uint8_t* __restrict__ qw,
                                                      const float* __restrict__ sx,
                                                      const float* __restrict__ wscale,
                                                      const float* __restrict__ bias,
                                                      float* __restrict__ out) {
  __shared__ uint8_t As[2][BM * BK] __attribute__((aligned(16)));  // 2 x 32 KB
  __shared__ uint8_t Bs[2][BN * BK] __attribute__((aligned(16)));  // 2 x 32 KB

  const int t = threadIdx.x;
  // bijective XCD swizzle: 512 blocks, 8 XCDs, 64 consecutive swz ids per XCD
  const int bid = blockIdx.y * gridDim.x + blockIdx.x;
  const int swz = ((bid & 7) << 6) | (bid >> 3);
  const int bx = swz & 15;   // n-tile (4096/256 = 16)
  const int by = swz >> 4;   // m-tile (8192/256 = 32)
  const int m0 = by * BM;
  const int n0 = bx * BN;

  const int lane = t & 63;
  const int wave = t >> 6;
  const int wr = wave >> 2;  // 0..1
  const int wc = wave & 3;   // 0..3
  const int lr = lane & 15;
  const int lq = lane >> 4;
  const int r7 = lr & 7;
  const int c0 = ((2 * lq) ^ r7) << 4;

  v4f acc[8][4] = {};

  // staging: 4 segments of 64 rows per operand per K-tile. Thread t covers
  // row rA = t>>3 of its segment, stored chunk t&7 <- logical chunk (t&7)^(rA&7).
  const int rA = t >> 3;
  const int csrc = (((t & 7) ^ (rA & 7)) << 4);
  const uint8_t* ga = qx + (size_t)(m0 + rA) * 4096 + csrc;
  const uint8_t* gb = qw + (size_t)(n0 + rA) * 4096 + csrc;
  const int ldst = t * 16;

  int arow[8], brow[4];
#pragma unroll
  for (int mt = 0; mt < 8; ++mt)
    arow[mt] = (wr * 128 + mt * 16 + lr) * BK + c0;
#pragma unroll
  for (int nt = 0; nt < 4; ++nt)
    brow[nt] = (wc * 64 + nt * 16 + lr) * BK + c0;

  // prologue: stage K-tile 0 -> buf0 and K-tile 1 -> buf1; wait for tile 0
  // only (8 oldest loads) -- tile 1's 8 remain in flight.
  STAGE8(As[0], Bs[0], 0);
  STAGE8(As[1], Bs[1], 128);
  asm volatile("s_waitcnt vmcnt(8)" ::: "memory");
  __builtin_amdgcn_s_barrier();

  for (int kt = 0; kt < 32; ++kt) {
    const uint8_t* As_c = As[kt & 1];
    const uint8_t* Bs_c = Bs[kt & 1];
    frag_u a[4], b[4];

    // one free-running block: 24 ds_read_b128 + 32 MFMA, compiler-interleaved
    LDA4(0);
    LDB4;
    MFMA_HALF(0);
    LDA4(4);          // overwrites a[0..3] (register reuse; WAR handled by RA)
    MFMA_HALF(4);

    // every wave issued MFMA #32 => its 24 reads completed => after this
    // barrier buf[cur] is fully consumed by ALL waves: safe to overwrite.
    __builtin_amdgcn_s_barrier();
    if (kt < 30) {
      STAGE8(As[kt & 1], Bs[kt & 1], (kt + 2) << 7);
      // kt+1's 8 loads (issued one tile ago) landed; kt+2's 8 stay in flight
      asm volatile("s_waitcnt vmcnt(8)" ::: "memory");
    } else {
      asm volatile("s_waitcnt vmcnt(0)" ::: "memory");  // tail drain
    }
    __builtin_amdgcn_s_barrier();  // publish buf[kt+1]
  }

  // epilogue: y = qy * sx[m] * ws[n] + bias[n]; C/D: col=lane&15, row=(lane>>4)*4+reg
  float wv[4], bv[4];
#pragma unroll
  for (int nt = 0; nt < 4; ++nt) {
    const int n = n0 + wc * 64 + nt * 16 + lr;
    wv[nt] = wscale[n];
    bv[nt] = bias[n];
  }
#pragma unroll
  for (int mt = 0; mt < 8; ++mt) {
#pragma unroll
    for (int r = 0; r < 4; ++r) {
      const int m = m0 + wr * 128 + mt * 16 + lq * 4 + r;
      const float sm = sx[m];
#pragma unroll
      for (int nt = 0; nt < 4; ++nt) {
        const int n = n0 + wc * 64 + nt * 16 + lr;
        out[(size_t)m * 4096 + n] = acc[mt][nt][r] * sm * wv[nt] + bv[nt];
      }
    }
  }
}

extern "C" void kernel_launch(void* const* d_in, const int* in_sizes, int n_in,
                              void* d_out, int out_size, void* d_ws, size_t ws_size,
                              hipStream_t stream) {
  const float* x = (const float*)d_in[0];
  const float* w = (const float*)d_in[1];
  const float* bias = (const float*)d_in[2];
  float* out = (float*)d_out;

  uint8_t* qx = (uint8_t*)d_ws;
  uint8_t* qw = qx + (size_t)8192 * 4096;
  float* wscale = (float*)(qw + (size_t)4096 * 4096);
  float* sxp = wscale + 4096;

  wquant_kernel<<<4096, 256, 0, stream>>>(w, qw, wscale);
  xquant_kernel<<<2048, 256, 0, stream>>>(x, qx, sxp);
  dim3 grid(4096 / BN, 8192 / BM);
  gemm_kernel<<<grid, 512, 0, stream>>>(qx, qw, sxp, wscale, bias, out);
}